// Round 1
// baseline (304.001 us; speedup 1.0000x reference)
//
#include <hip/hip_runtime.h>
#include <math.h>

#define Bn 4
#define Cn 64
#define On 64
#define Hn 128
#define Wn 128
#define Kn 9
#define HWn (Hn*Wn)

// ---------------------------------------------------------------------------
// Prep kernel: blocks 0..1023 transpose x_main NCHW -> NHWC (xT[b][h*W+w][c]).
// block 1024 repacks weight -> W3[k][og][c][oi] (oi contiguous for s_load x16)
// block 1025 repacks w_om   -> WOM3[c][j][q]    (per-c contiguous 243 floats)
// ---------------------------------------------------------------------------
__global__ __launch_bounds__(256) void prep_kernel(
    const float* __restrict__ x_main,
    const float* __restrict__ weight,
    const float* __restrict__ w_om,
    float* __restrict__ xT,
    float* __restrict__ W3,
    float* __restrict__ WOM3)
{
  int blk = blockIdx.x;
  int t = threadIdx.x;
  if (blk < 1024) {
    __shared__ float tile[64 * 65];
    int b   = blk >> 8;          // 256 tiles per batch
    int p0  = (blk & 255) << 6;  // 64-pixel tile
    int lane = t & 63;
    int grp  = t >> 6;
    const float* src = x_main + (b * Cn) * HWn;
    #pragma unroll
    for (int i = 0; i < 16; ++i) {
      int c = i * 4 + grp;
      tile[c * 65 + lane] = src[c * HWn + p0 + lane];   // coalesced read
    }
    __syncthreads();
    float* dst = xT + (b * HWn + p0) * Cn;
    #pragma unroll
    for (int i = 0; i < 16; ++i) {
      int p = i * 4 + grp;
      dst[p * Cn + lane] = tile[lane * 65 + p];          // coalesced write
    }
  } else if (blk == 1024) {
    for (int idx = t; idx < On * Cn * 9; idx += 256) {
      int o = idx / 576;
      int rem = idx - o * 576;
      int c = rem / 9;
      int k = rem - c * 9;
      W3[(((k * 4 + (o >> 4)) * 64 + c) << 4) + (o & 15)] = weight[idx];
    }
  } else {
    for (int idx = t; idx < 27 * Cn * 9; idx += 256) {
      int j = idx / 576;
      int rem = idx - j * 576;
      int c = rem / 9;
      int q = rem - c * 9;
      WOM3[c * 243 + j * 9 + q] = w_om[idx];
    }
  }
}

// ---------------------------------------------------------------------------
// Main fused kernel. One block = 256 threads = 4 waves handles (b, h, 64 w's).
// Phase A: 27-ch 3x3 conv on x_extra (c-split over 4 waves, wave-uniform
//          weights -> s_load), LDS reduce, offsets/mask -> LDS.
// Phase B: per k: gather+interp S[pix][c] (lane=c, coalesced NHWC loads),
//          then fp32 GEMM accumulate (lane=pix, 16 o per thread).
// ---------------------------------------------------------------------------
__global__ __launch_bounds__(256, 4) void dcn_main(
    const float* __restrict__ xT,
    const float* __restrict__ x_extra,
    const float* __restrict__ pre_offset,
    const float* __restrict__ pre_sim,
    const float* __restrict__ W3,
    const float* __restrict__ bias,
    const float* __restrict__ WOM3,
    const float* __restrict__ b_om,
    float* __restrict__ out)
{
  __shared__ float s_buf[4 * 64 * 29];   // phase A partials; reused as S[64][65]
  __shared__ float s_py[9 * 64];
  __shared__ float s_px[9 * 64];
  __shared__ float s_m [9 * 64];

  const int t    = threadIdx.x;
  const int lane = t & 63;
  const int wv   = __builtin_amdgcn_readfirstlane(t >> 6);
  const int blk  = blockIdx.x;
  const int b    = blk >> 8;
  const int hs   = blk & 255;
  const int h    = hs >> 1;
  const int w0   = (hs & 1) << 6;
  const int w    = w0 + lane;

  // ---- Phase A: conv partials, channels [wv*16, wv*16+16)
  float acc[27];
  #pragma unroll
  for (int j = 0; j < 27; ++j) acc[j] = 0.f;

  {
    const float* xe = x_extra + (b * Cn + wv * 16) * HWn;
    for (int ci = 0; ci < 16; ++ci) {
      const float* xc = xe + ci * HWn;
      float tap[9];
      #pragma unroll
      for (int r = 0; r < 3; ++r) {
        int hh = h - 1 + r;
        bool hv = (hh >= 0) & (hh < Hn);
        #pragma unroll
        for (int s = 0; s < 3; ++s) {
          int ww = w - 1 + s;
          bool vv = hv & (ww >= 0) & (ww < Wn);
          tap[r * 3 + s] = vv ? xc[hh * Wn + ww] : 0.f;
        }
      }
      const float* wp = WOM3 + (wv * 16 + ci) * 243;  // wave-uniform -> s_load
      #pragma unroll
      for (int j = 0; j < 27; ++j) {
        #pragma unroll
        for (int q = 0; q < 9; ++q)
          acc[j] = fmaf(tap[q], wp[j * 9 + q], acc[j]);
      }
    }
  }
  #pragma unroll
  for (int j = 0; j < 27; ++j)
    s_buf[(wv * 64 + lane) * 29 + j] = acc[j];   // stride 29: conflict-free
  __syncthreads();

  // ---- offsets/mask: waves 0..2 handle 3 k's each
  if (wv < 3) {
    #pragma unroll
    for (int kk = 0; kk < 3; ++kk) {
      int k = wv * 3 + kk;
      float sy = b_om[2 * k], sx = b_om[2 * k + 1], sm = b_om[18 + k];
      #pragma unroll
      for (int q = 0; q < 4; ++q) {
        const float* rp = &s_buf[(q * 64 + lane) * 29];
        sy += rp[2 * k];
        sx += rp[2 * k + 1];
        sm += rp[18 + k];
      }
      int pbase = ((b * Kn + k) * Hn + h) * Wn + w;
      float oy = 10.f * tanhf(sy) + pre_offset[pbase * 2 + 1];
      float ox = 10.f * tanhf(sx) + pre_offset[pbase * 2 + 0];
      float m  = 1.f / (1.f + expf(-sm * pre_sim[pbase]));
      s_py[k * 64 + lane] = oy + (float)(h - 1 + k / 3);
      s_px[k * 64 + lane] = ox + (float)(w - 1 + k % 3);
      s_m [k * 64 + lane] = m;
    }
  }
  __syncthreads();

  // ---- Phase B
  float yacc[16];
  #pragma unroll
  for (int i = 0; i < 16; ++i) yacc[i] = 0.f;

  const float* xb = xT + b * HWn * Cn;

  for (int k = 0; k < 9; ++k) {
    // B1: lane = channel, wave covers pixels [wv*16, wv*16+16)
    #pragma unroll
    for (int i = 0; i < 16; ++i) {
      int pix = wv * 16 + i;
      float py = s_py[k * 64 + pix];
      float px = s_px[k * 64 + pix];
      float m  = s_m [k * 64 + pix];
      float fy = floorf(py), fx = floorf(px);
      float dy = py - fy, dx = px - fx;
      int y0 = (int)fy, x0 = (int)fx;
      int y1 = y0 + 1, x1 = x0 + 1;
      int yc0 = min(max(y0, 0), Hn - 1), yc1 = min(max(y1, 0), Hn - 1);
      int xc0 = min(max(x0, 0), Wn - 1), xc1 = min(max(x1, 0), Wn - 1);
      bool vy0 = (y0 >= 0) & (y0 < Hn);
      bool vy1 = (y1 >= 0) & (y1 < Hn);
      bool vx0 = (x0 >= 0) & (x0 < Wn);
      bool vx1 = (x1 >= 0) & (x1 < Wn);
      const float* r0 = xb + (yc0 * Wn) * Cn;
      const float* r1 = xb + (yc1 * Wn) * Cn;
      float v00 = r0[xc0 * Cn + lane];   // 256B coalesced across lanes
      float v01 = r0[xc1 * Cn + lane];
      float v10 = r1[xc0 * Cn + lane];
      float v11 = r1[xc1 * Cn + lane];
      float w00 = (vy0 & vx0) ? (1.f - dy) * (1.f - dx) * m : 0.f;
      float w01 = (vy0 & vx1) ? (1.f - dy) * dx * m : 0.f;
      float w10 = (vy1 & vx0) ? dy * (1.f - dx) * m : 0.f;
      float w11 = (vy1 & vx1) ? dy * dx * m : 0.f;
      float sv = v00 * w00 + v01 * w01 + v10 * w10 + v11 * w11;
      s_buf[pix * 65 + lane] = sv;       // conflict-free
    }
    __syncthreads();

    // B2: lane = pixel, wave covers o in [wv*16, wv*16+16)
    {
      const float* wp = W3 + ((k * 4 + wv) * 64) * 16;  // wave-uniform
      #pragma unroll 2
      for (int c = 0; c < 64; ++c) {
        float sv = s_buf[lane * 65 + c];                // conflict-free
        const float* wc = wp + c * 16;
        #pragma unroll
        for (int oi = 0; oi < 16; ++oi)
          yacc[oi] = fmaf(sv, wc[oi], yacc[oi]);
      }
    }
    __syncthreads();
  }

  // ---- epilogue
  {
    const float* bp = bias + wv * 16;
    float* op = out + ((b * On + wv * 16) * Hn + h) * Wn + w0 + lane;
    #pragma unroll
    for (int oi = 0; oi < 16; ++oi)
      op[oi * HWn] = yacc[oi] + bp[oi];   // coalesced
  }
}

extern "C" void kernel_launch(void* const* d_in, const int* in_sizes, int n_in,
                              void* d_out, int out_size, void* d_ws, size_t ws_size,
                              hipStream_t stream) {
  const float* x_main     = (const float*)d_in[0];
  const float* x_extra    = (const float*)d_in[1];
  const float* pre_offset = (const float*)d_in[2];
  const float* pre_sim    = (const float*)d_in[3];
  const float* weight     = (const float*)d_in[4];
  const float* bias       = (const float*)d_in[5];
  const float* w_om       = (const float*)d_in[6];
  const float* b_om       = (const float*)d_in[7];
  float* out = (float*)d_out;

  char* ws = (char*)d_ws;
  float* xT   = (float*)(ws);                          // 16,777,216 B
  float* W3   = (float*)(ws + 16777216);               //    147,456 B
  float* WOM3 = (float*)(ws + 16777216 + 147456);      //     62,208 B

  prep_kernel<<<1026, 256, 0, stream>>>(x_main, weight, w_om, xT, W3, WOM3);
  dcn_main<<<1024, 256, 0, stream>>>(xT, x_extra, pre_offset, pre_sim,
                                     W3, bias, WOM3, b_om, out);
}

// Round 2
// 278.834 us; speedup vs baseline: 1.0903x; 1.0903x over previous
//
#include <hip/hip_runtime.h>
#include <math.h>

#define Bn 4
#define Cn 64
#define On 64
#define Hn 128
#define Wn 128
#define Kn 9
#define HWn (Hn*Wn)

typedef short v8s __attribute__((ext_vector_type(8)));
typedef float v16f __attribute__((ext_vector_type(16)));

__device__ inline unsigned short f2bf(float f) {
  unsigned u = __builtin_bit_cast(unsigned, f);
  u += 0x7fff + ((u >> 16) & 1);          // round-to-nearest-even
  return (unsigned short)(u >> 16);
}
__device__ inline float bf2f(unsigned short h) {
  unsigned u = ((unsigned)h) << 16;
  return __builtin_bit_cast(float, u);
}

// ---------------------------------------------------------------------------
// Prep: blocks 0..1023: x_main NCHW fp32 -> NHWC bf16 (xT[b][p][c]).
// block 1024: weight -> A-fragment order for mfma_32x32x16_bf16:
//   Wfrag[k][oh][chunk][lane][j] ; o = oh*32 + (lane&31), c = chunk*16 + (lane>>5)*8 + j
// block 1025: w_om -> WOM3[c][j][q] fp32 (per-c contiguous 243)
// ---------------------------------------------------------------------------
__global__ __launch_bounds__(256) void prep_kernel(
    const float* __restrict__ x_main,
    const float* __restrict__ weight,
    const float* __restrict__ w_om,
    unsigned short* __restrict__ xT,
    unsigned short* __restrict__ Wfrag,
    float* __restrict__ WOM3)
{
  int blk = blockIdx.x;
  int t = threadIdx.x;
  if (blk < 1024) {
    __shared__ float tile[64 * 65];
    int b   = blk >> 8;
    int p0  = (blk & 255) << 6;
    int lane = t & 63;
    int grp  = t >> 6;
    const float* src = x_main + (b * Cn) * HWn;
    #pragma unroll
    for (int i = 0; i < 16; ++i) {
      int c = i * 4 + grp;
      tile[c * 65 + lane] = src[c * HWn + p0 + lane];   // coalesced read
    }
    __syncthreads();
    unsigned short* dst = xT + (b * HWn + p0) * Cn;
    #pragma unroll
    for (int i = 0; i < 16; ++i) {
      int p = i * 4 + grp;
      dst[p * Cn + lane] = f2bf(tile[lane * 65 + p]);   // coalesced write
    }
  } else if (blk == 1024) {
    // 9*2*4*64*8 = 36864 elements
    for (int idx = t; idx < 36864; idx += 256) {
      int j    = idx & 7;
      int lane = (idx >> 3) & 63;
      int q    = (idx >> 9) & 3;
      int oh   = (idx >> 11) & 1;
      int k    = idx >> 12;
      int o = oh * 32 + (lane & 31);
      int c = q * 16 + (lane >> 5) * 8 + j;
      Wfrag[idx] = f2bf(weight[(o * Cn + c) * 9 + k]);
    }
  } else {
    for (int idx = t; idx < 27 * Cn * 9; idx += 256) {
      int j = idx / 576;
      int rem = idx - j * 576;
      int c = rem / 9;
      int q = rem - c * 9;
      WOM3[c * 243 + j * 9 + q] = w_om[idx];
    }
  }
}

// ---------------------------------------------------------------------------
// Main fused kernel. One block = 4 waves = (b, h, 64 w's).
// Phase A: 27-ch 3x3 fp32 conv on x_extra (c-split over waves), LDS reduce,
//          offsets/mask -> LDS.
// Phase B per k: B1 gather+interp (lane=c, coalesced bf16 NHWC loads) ->
//          XOR-swizzled bf16 S in LDS; B2: mfma_32x32x16_bf16, wave wv does
//          output tile (oh=wv>>1, ph=wv&1).
// ---------------------------------------------------------------------------
__global__ __launch_bounds__(256, 4) void dcn_main(
    const unsigned short* __restrict__ xT,
    const float* __restrict__ x_extra,
    const float* __restrict__ pre_offset,
    const float* __restrict__ pre_sim,
    const unsigned short* __restrict__ Wfrag,
    const float* __restrict__ bias,
    const float* __restrict__ WOM3,
    const float* __restrict__ b_om,
    float* __restrict__ out)
{
  __shared__ float s_buf[4 * 64 * 29];   // conv partials; first 8KB reused as S
  __shared__ float s_py[9 * 64];
  __shared__ float s_px[9 * 64];
  __shared__ float s_m [9 * 64];
  unsigned short* sS = (unsigned short*)s_buf;   // S[pix][64] bf16, XOR-swizzled

  const int t    = threadIdx.x;
  const int lane = t & 63;
  const int wv   = __builtin_amdgcn_readfirstlane(t >> 6);
  const int blk  = blockIdx.x;
  const int b    = blk >> 8;
  const int hs   = blk & 255;
  const int h    = hs >> 1;
  const int w0   = (hs & 1) << 6;
  const int w    = w0 + lane;

  // ---- Phase A: conv partials, channels [wv*16, wv*16+16)
  float acc[27];
  #pragma unroll
  for (int j = 0; j < 27; ++j) acc[j] = 0.f;
  {
    const float* xe = x_extra + (b * Cn + wv * 16) * HWn;
    for (int ci = 0; ci < 16; ++ci) {
      const float* xc = xe + ci * HWn;
      float tap[9];
      #pragma unroll
      for (int r = 0; r < 3; ++r) {
        int hh = h - 1 + r;
        bool hv = (hh >= 0) & (hh < Hn);
        #pragma unroll
        for (int s = 0; s < 3; ++s) {
          int ww = w - 1 + s;
          bool vv = hv & (ww >= 0) & (ww < Wn);
          tap[r * 3 + s] = vv ? xc[hh * Wn + ww] : 0.f;
        }
      }
      const float* wp = WOM3 + (wv * 16 + ci) * 243;  // wave-uniform -> s_load
      #pragma unroll
      for (int j = 0; j < 27; ++j) {
        #pragma unroll
        for (int q = 0; q < 9; ++q)
          acc[j] = fmaf(tap[q], wp[j * 9 + q], acc[j]);
      }
    }
  }
  #pragma unroll
  for (int j = 0; j < 27; ++j)
    s_buf[(wv * 64 + lane) * 29 + j] = acc[j];   // stride 29: conflict-free
  __syncthreads();

  // ---- offsets/mask: waves 0..2 handle 3 k's each (lane = pix)
  if (wv < 3) {
    #pragma unroll
    for (int kk = 0; kk < 3; ++kk) {
      int k = wv * 3 + kk;
      float sy = b_om[2 * k], sx = b_om[2 * k + 1], sm = b_om[18 + k];
      #pragma unroll
      for (int q = 0; q < 4; ++q) {
        const float* rp = &s_buf[(q * 64 + lane) * 29];
        sy += rp[2 * k];
        sx += rp[2 * k + 1];
        sm += rp[18 + k];
      }
      int pbase = ((b * Kn + k) * Hn + h) * Wn + w;
      float oy = 10.f * tanhf(sy) + pre_offset[pbase * 2 + 1];
      float ox = 10.f * tanhf(sx) + pre_offset[pbase * 2 + 0];
      float m  = 1.f / (1.f + expf(-sm * pre_sim[pbase]));
      s_py[k * 64 + lane] = oy + (float)(h - 1 + k / 3);
      s_px[k * 64 + lane] = ox + (float)(w - 1 + k % 3);
      s_m [k * 64 + lane] = m;
    }
  }
  __syncthreads();

  // ---- Phase B
  const int oh = wv >> 1;          // o-half for MFMA tile
  const int ph = wv & 1;           // pix-half
  const int n  = lane & 31;
  const int kh_ = lane >> 5;       // k-group within fragment

  v16f yacc = {0,0,0,0,0,0,0,0,0,0,0,0,0,0,0,0};

  const unsigned short* xb = xT + b * HWn * Cn;
  const v8s* Wf = (const v8s*)Wfrag;

  for (int k = 0; k < 9; ++k) {
    // A-fragments for this k (global, L2-hot) — issue before B1 to hide latency
    const v8s* wk = Wf + ((k * 2 + oh) * 4) * 64 + lane;
    v8s a0 = wk[0];
    v8s a1 = wk[64];
    v8s a2 = wk[128];
    v8s a3 = wk[192];

    // B1: lane = channel, wave covers pixels [wv*16, wv*16+16)
    #pragma unroll 4
    for (int i = 0; i < 16; ++i) {
      int pix = wv * 16 + i;
      float py = s_py[k * 64 + pix];
      float px = s_px[k * 64 + pix];
      float m  = s_m [k * 64 + pix];
      float fy = floorf(py), fx = floorf(px);
      float dy = py - fy, dx = px - fx;
      int y0 = (int)fy, x0 = (int)fx;
      int y1 = y0 + 1, x1 = x0 + 1;
      int yc0 = min(max(y0, 0), Hn - 1), yc1 = min(max(y1, 0), Hn - 1);
      int xc0 = min(max(x0, 0), Wn - 1), xc1 = min(max(x1, 0), Wn - 1);
      bool vy0 = (y0 >= 0) & (y0 < Hn);
      bool vy1 = (y1 >= 0) & (y1 < Hn);
      bool vx0 = (x0 >= 0) & (x0 < Wn);
      bool vx1 = (x1 >= 0) & (x1 < Wn);
      const unsigned short* r0 = xb + (yc0 * Wn) * Cn;
      const unsigned short* r1 = xb + (yc1 * Wn) * Cn;
      float v00 = bf2f(r0[xc0 * Cn + lane]);   // coalesced 128B across lanes
      float v01 = bf2f(r0[xc1 * Cn + lane]);
      float v10 = bf2f(r1[xc0 * Cn + lane]);
      float v11 = bf2f(r1[xc1 * Cn + lane]);
      float w00 = (vy0 & vx0) ? (1.f - dy) * (1.f - dx) * m : 0.f;
      float w01 = (vy0 & vx1) ? (1.f - dy) * dx * m : 0.f;
      float w10 = (vy1 & vx0) ? dy * (1.f - dx) * m : 0.f;
      float w11 = (vy1 & vx1) ? dy * dx * m : 0.f;
      float sv = v00 * w00 + v01 * w01 + v10 * w10 + v11 * w11;
      // XOR-swizzled: slot = (c>>3) ^ (pix&7); write stays conflict-free
      sS[pix * 64 + ((((lane >> 3) ^ (pix & 7)) << 3) | (lane & 7))] = f2bf(sv);
    }
    __syncthreads();

    // B2: one mfma_32x32x16 tile per wave; B-frags via swizzled ds_read_b128
    {
      const char* srow = (const char*)sS + (ph * 32 + n) * 128;
      v8s b0 = *(const v8s*)(srow + (((0 * 2 + kh_) ^ (n & 7)) << 4));
      v8s b1 = *(const v8s*)(srow + (((1 * 2 + kh_) ^ (n & 7)) << 4));
      v8s b2 = *(const v8s*)(srow + (((2 * 2 + kh_) ^ (n & 7)) << 4));
      v8s b3 = *(const v8s*)(srow + (((3 * 2 + kh_) ^ (n & 7)) << 4));
      yacc = __builtin_amdgcn_mfma_f32_32x32x16_bf16(a0, b0, yacc, 0, 0, 0);
      yacc = __builtin_amdgcn_mfma_f32_32x32x16_bf16(a1, b1, yacc, 0, 0, 0);
      yacc = __builtin_amdgcn_mfma_f32_32x32x16_bf16(a2, b2, yacc, 0, 0, 0);
      yacc = __builtin_amdgcn_mfma_f32_32x32x16_bf16(a3, b3, yacc, 0, 0, 0);
    }
    __syncthreads();
  }

  // ---- epilogue: D layout col=lane&31 (pix), row=(reg&3)+8*(reg>>2)+4*(lane>>5)
  {
    float* ob = out + (b * On) * HWn + h * Wn + w0 + ph * 32 + n;
    #pragma unroll
    for (int reg = 0; reg < 16; ++reg) {
      int o = oh * 32 + (reg & 3) + 8 * (reg >> 2) + 4 * kh_;
      ob[o * HWn] = yacc[reg] + bias[o];
    }
  }
}

extern "C" void kernel_launch(void* const* d_in, const int* in_sizes, int n_in,
                              void* d_out, int out_size, void* d_ws, size_t ws_size,
                              hipStream_t stream) {
  const float* x_main     = (const float*)d_in[0];
  const float* x_extra    = (const float*)d_in[1];
  const float* pre_offset = (const float*)d_in[2];
  const float* pre_sim    = (const float*)d_in[3];
  const float* weight     = (const float*)d_in[4];
  const float* bias       = (const float*)d_in[5];
  const float* w_om       = (const float*)d_in[6];
  const float* b_om       = (const float*)d_in[7];
  float* out = (float*)d_out;

  char* ws = (char*)d_ws;
  unsigned short* xT    = (unsigned short*)(ws);                 // 8,388,608 B
  unsigned short* Wfrag = (unsigned short*)(ws + 8388608);       //    73,728 B
  float*          WOM3  = (float*)(ws + 8388608 + 73728);        //    62,208 B

  prep_kernel<<<1026, 256, 0, stream>>>(x_main, weight, w_om, xT, Wfrag, WOM3);
  dcn_main<<<1024, 256, 0, stream>>>(xT, x_extra, pre_offset, pre_sim,
                                     Wfrag, bias, WOM3, b_om, out);
}

// Round 3
// 214.957 us; speedup vs baseline: 1.4142x; 1.2972x over previous
//
#include <hip/hip_runtime.h>
#include <math.h>

#define Bn 4
#define Cn 64
#define On 64
#define Hn 128
#define Wn 128
#define Kn 9
#define HWn (Hn*Wn)
#define ZROW 16384            // per-batch zero row index in xT
#define XBSTRIDE (16385*64)   // per-batch stride of xT (16384 rows + 1 zero row)

typedef short v8s __attribute__((ext_vector_type(8)));
typedef float v4f __attribute__((ext_vector_type(4)));

__device__ inline unsigned short f2bf(float f) {
  unsigned u = __builtin_bit_cast(unsigned, f);
  u += 0x7fff + ((u >> 16) & 1);          // RNE
  return (unsigned short)(u >> 16);
}
__device__ inline float bf2f(unsigned short h) {
  unsigned u = ((unsigned)h) << 16;
  return __builtin_bit_cast(float, u);
}
__device__ inline unsigned short f2h(float f) {
  _Float16 h = (_Float16)f;
  return __builtin_bit_cast(unsigned short, h);
}
__device__ inline float h2f(unsigned v) {
  _Float16 h = __builtin_bit_cast(_Float16, (unsigned short)(v & 0xffff));
  return (float)h;
}

// ---------------------------------------------------------------------------
// K1: blocks 0..511        : x_main NCHW fp32 -> xT NHWC bf16 (+zero row/batch)
//     blocks 512..1535     : offset conv -> OFS records {4xu16 row, 4xf16 w}
//     block 1536           : weight -> Wfrag (16x16x32 A-frag order) + zero rows
// ---------------------------------------------------------------------------
__global__ __launch_bounds__(256) void prep_kernel(
    const float* __restrict__ x_main,
    const float* __restrict__ x_extra,
    const float* __restrict__ pre_offset,
    const float* __restrict__ pre_sim,
    const float* __restrict__ weight,
    const float* __restrict__ w_om,
    const float* __restrict__ b_om,
    unsigned short* __restrict__ xT,
    unsigned short* __restrict__ Wfrag,
    uint4* __restrict__ OFS)
{
  const int blk = blockIdx.x;
  const int t = threadIdx.x;
  const int lane = t & 63;

  if (blk < 512) {
    // ---- transpose: block = (b, 128-pixel tile)
    __shared__ float tile[64 * 129];
    int b  = blk >> 7;
    int p0 = (blk & 127) << 7;
    int grp = t >> 6;
    const float* src = x_main + b * Cn * HWn + p0;
    #pragma unroll
    for (int i = 0; i < 16; ++i) {
      int c = i * 4 + grp;
      tile[c * 129 + lane]      = src[c * HWn + lane];        // 256B coalesced
      tile[c * 129 + 64 + lane] = src[c * HWn + 64 + lane];
    }
    __syncthreads();
    unsigned short* dst = xT + b * XBSTRIDE + p0 * 64;
    #pragma unroll
    for (int i = 0; i < 32; ++i) {
      int p = i * 4 + grp;
      dst[p * 64 + lane] = f2bf(tile[lane * 129 + p]);        // stride129: no conflict
    }
  } else if (blk < 1536) {
    // ---- offset conv: block = (b, h, 64 w's); 4 waves c-split
    __shared__ float s_buf[4 * 64 * 29];
    int oblk = blk - 512;
    int b  = oblk >> 8;
    int hs = oblk & 255;
    int h  = hs >> 1;
    int w0 = (hs & 1) << 6;
    int w  = w0 + lane;
    int wv = __builtin_amdgcn_readfirstlane(t >> 6);

    float acc[27];
    #pragma unroll
    for (int j = 0; j < 27; ++j) acc[j] = 0.f;
    {
      const float* xe = x_extra + (b * Cn + wv * 16) * HWn;
      for (int ci = 0; ci < 16; ++ci) {
        const float* xc = xe + ci * HWn;
        float tap[9];
        #pragma unroll
        for (int r = 0; r < 3; ++r) {
          int hh = h - 1 + r;
          bool hv = (hh >= 0) & (hh < Hn);
          #pragma unroll
          for (int s = 0; s < 3; ++s) {
            int ww = w - 1 + s;
            bool vv = hv & (ww >= 0) & (ww < Wn);
            tap[r * 3 + s] = vv ? xc[hh * Wn + ww] : 0.f;
          }
        }
        const float* wp = w_om + (wv * 16 + ci) * 9;   // w_om[j][c][q]
        #pragma unroll
        for (int j = 0; j < 27; ++j) {
          #pragma unroll
          for (int q = 0; q < 9; ++q)
            acc[j] = fmaf(tap[q], wp[j * 576 + q], acc[j]);  // wave-uniform
        }
      }
    }
    #pragma unroll
    for (int j = 0; j < 27; ++j)
      s_buf[(wv * 64 + lane) * 29 + j] = acc[j];
    __syncthreads();

    if (wv < 3) {
      #pragma unroll
      for (int kk = 0; kk < 3; ++kk) {
        int k = wv * 3 + kk;
        float sy = b_om[2 * k], sx = b_om[2 * k + 1], sm = b_om[18 + k];
        #pragma unroll
        for (int q = 0; q < 4; ++q) {
          const float* rp = &s_buf[(q * 64 + lane) * 29];
          sy += rp[2 * k];
          sx += rp[2 * k + 1];
          sm += rp[18 + k];
        }
        int pbase = ((b * Kn + k) * Hn + h) * Wn + w;
        float py = 10.f * tanhf(sy) + pre_offset[pbase * 2 + 1] + (float)(h - 1 + k / 3);
        float px = 10.f * tanhf(sx) + pre_offset[pbase * 2 + 0] + (float)(w - 1 + k % 3);
        float m  = 1.f / (1.f + expf(-sm * pre_sim[pbase]));
        float fy = floorf(py), fx = floorf(px);
        float dy = py - fy, dx = px - fx;
        int y0 = (int)fy, x0 = (int)fx;
        int y1 = y0 + 1, x1 = x0 + 1;
        bool vy0 = (y0 >= 0) & (y0 < Hn), vy1 = (y1 >= 0) & (y1 < Hn);
        bool vx0 = (x0 >= 0) & (x0 < Wn), vx1 = (x1 >= 0) & (x1 < Wn);
        unsigned r00 = (vy0 & vx0) ? (unsigned)(y0 * Wn + x0) : ZROW;
        unsigned r01 = (vy0 & vx1) ? (unsigned)(y0 * Wn + x1) : ZROW;
        unsigned r10 = (vy1 & vx0) ? (unsigned)(y1 * Wn + x0) : ZROW;
        unsigned r11 = (vy1 & vx1) ? (unsigned)(y1 * Wn + x1) : ZROW;
        float wy0 = 1.f - dy, wx0 = 1.f - dx;
        uint4 rec;
        rec.x = r00 | (r01 << 16);
        rec.y = r10 | (r11 << 16);
        rec.z = (unsigned)f2h(wy0 * wx0 * m) | ((unsigned)f2h(wy0 * dx * m) << 16);
        rec.w = (unsigned)f2h(dy * wx0 * m) | ((unsigned)f2h(dy * dx * m) << 16);
        OFS[((((b * Hn + h) * 8) + (w >> 4)) * Kn + k) * 16 + (w & 15)] = rec;
      }
    }
  } else {
    // ---- Wfrag repack: A[m=lane&15][c=hk*32+(lane>>4)*8+j] for o-tile ot, k
    for (int idx = t; idx < 36864; idx += 256) {
      int j  = idx & 7;
      int ln = (idx >> 3) & 63;
      int hk = (idx >> 9) & 1;
      int ot = (idx >> 10) & 3;
      int k  = idx >> 12;
      int o = ot * 16 + (ln & 15);
      int c = hk * 32 + (ln >> 4) * 8 + j;
      Wfrag[idx] = f2bf(weight[(o * Cn + c) * Kn + k]);
    }
    // zero rows (one per batch)
    if (t < 256) {
      int b = t >> 6, c = t & 63;
      xT[b * XBSTRIDE + ZROW * 64 + c] = 0;
    }
  }
}

// ---------------------------------------------------------------------------
// K2 main: barrier-free. One wave = (b, h, 16-pixel group): gathers its own
// 16px x 64c S tile (records via s_load), within-wave LDS transpose
// (XOR-swizzled), 8x mfma_f32_16x16x32_bf16 per k.
// ---------------------------------------------------------------------------
__global__ __launch_bounds__(256, 4) void dcn_main(
    const unsigned short* __restrict__ xT,
    const unsigned short* __restrict__ Wfrag,
    const uint4* __restrict__ OFS,
    const float* __restrict__ bias,
    float* __restrict__ out)
{
  __shared__ unsigned short sS[4 * 16 * 64];   // 2KB per wave

  const int t    = threadIdx.x;
  const int lane = t & 63;
  const int wv   = __builtin_amdgcn_readfirstlane(t >> 6);
  const int blk  = blockIdx.x;
  const int b    = blk >> 8;
  const int h    = (blk >> 1) & 127;
  const int wq   = (blk & 1) * 4 + wv;         // 16-pixel group index (0..7)

  const unsigned short* xb = xT + b * XBSTRIDE;
  const uint4* recs = OFS + (((b * Hn + h) * 8) + wq) * Kn * 16;
  unsigned short* sw = sS + wv * 1024;

  const int kq = lane >> 4;    // k-quad within fragment
  const int n  = lane & 15;    // pixel within tile / o within tile

  v4f acc0 = {0,0,0,0}, acc1 = {0,0,0,0}, acc2 = {0,0,0,0}, acc3 = {0,0,0,0};

  const v8s* Wf = (const v8s*)Wfrag;

  for (int k = 0; k < Kn; ++k) {
    // A-fragments (weights, L2-hot): 8 x 16B coalesced loads
    const v8s* wk = Wf + (k * 8) * 64 + lane;
    v8s A0 = wk[0 * 64], A1 = wk[1 * 64], A2 = wk[2 * 64], A3 = wk[3 * 64];
    v8s A4 = wk[4 * 64], A5 = wk[5 * 64], A6 = wk[6 * 64], A7 = wk[7 * 64];

    // B1: gather + interp 16 pixels (lane = channel)
    #pragma unroll 4
    for (int i = 0; i < 16; ++i) {
      uint4 rec = recs[k * 16 + i];             // wave-uniform -> s_load
      const unsigned short* p00 = xb + (rec.x & 0xffff) * 64;
      const unsigned short* p01 = xb + (rec.x >> 16) * 64;
      const unsigned short* p10 = xb + (rec.y & 0xffff) * 64;
      const unsigned short* p11 = xb + (rec.y >> 16) * 64;
      float v00 = bf2f(p00[lane]);              // 128B coalesced
      float v01 = bf2f(p01[lane]);
      float v10 = bf2f(p10[lane]);
      float v11 = bf2f(p11[lane]);
      float sv = fmaf(v00, h2f(rec.z),
                 fmaf(v01, h2f(rec.z >> 16),
                 fmaf(v10, h2f(rec.w), v11 * h2f(rec.w >> 16))));
      sw[i * 64 + ((((lane >> 3) ^ (i & 7)) << 3) | (lane & 7))] = f2bf(sv);
    }

    // B-fragments: within-wave LDS read (no barrier needed), swizzle-matched
    const v8s* sv8 = (const v8s*)(sw + n * 64);
    v8s B0 = sv8[(0 * 4 + kq) ^ (n & 7)];
    v8s B1 = sv8[(1 * 4 + kq) ^ (n & 7)];

    acc0 = __builtin_amdgcn_mfma_f32_16x16x32_bf16(A0, B0, acc0, 0, 0, 0);
    acc0 = __builtin_amdgcn_mfma_f32_16x16x32_bf16(A1, B1, acc0, 0, 0, 0);
    acc1 = __builtin_amdgcn_mfma_f32_16x16x32_bf16(A2, B0, acc1, 0, 0, 0);
    acc1 = __builtin_amdgcn_mfma_f32_16x16x32_bf16(A3, B1, acc1, 0, 0, 0);
    acc2 = __builtin_amdgcn_mfma_f32_16x16x32_bf16(A4, B0, acc2, 0, 0, 0);
    acc2 = __builtin_amdgcn_mfma_f32_16x16x32_bf16(A5, B1, acc2, 0, 0, 0);
    acc3 = __builtin_amdgcn_mfma_f32_16x16x32_bf16(A6, B0, acc3, 0, 0, 0);
    acc3 = __builtin_amdgcn_mfma_f32_16x16x32_bf16(A7, B1, acc3, 0, 0, 0);
  }

  // epilogue: D col=lane&15 (pix), row=(lane>>4)*4+reg (o within tile)
  const float4* b4 = (const float4*)bias;
  float4 vb0 = b4[0 * 4 + kq], vb1 = b4[1 * 4 + kq], vb2 = b4[2 * 4 + kq], vb3 = b4[3 * 4 + kq];
  float* ob = out + (b * On) * HWn + h * Wn + wq * 16 + n;
  #pragma unroll
  for (int reg = 0; reg < 4; ++reg) {
    ob[(0 * 16 + kq * 4 + reg) * HWn] = acc0[reg] + ((const float*)&vb0)[reg];
    ob[(1 * 16 + kq * 4 + reg) * HWn] = acc1[reg] + ((const float*)&vb1)[reg];
    ob[(2 * 16 + kq * 4 + reg) * HWn] = acc2[reg] + ((const float*)&vb2)[reg];
    ob[(3 * 16 + kq * 4 + reg) * HWn] = acc3[reg] + ((const float*)&vb3)[reg];
  }
}

extern "C" void kernel_launch(void* const* d_in, const int* in_sizes, int n_in,
                              void* d_out, int out_size, void* d_ws, size_t ws_size,
                              hipStream_t stream) {
  const float* x_main     = (const float*)d_in[0];
  const float* x_extra    = (const float*)d_in[1];
  const float* pre_offset = (const float*)d_in[2];
  const float* pre_sim    = (const float*)d_in[3];
  const float* weight     = (const float*)d_in[4];
  const float* bias       = (const float*)d_in[5];
  const float* w_om       = (const float*)d_in[6];
  const float* b_om       = (const float*)d_in[7];
  float* out = (float*)d_out;

  char* ws = (char*)d_ws;
  unsigned short* xT    = (unsigned short*)(ws);              //  8,389,120 B
  unsigned short* Wfrag = (unsigned short*)(ws + 8389120);    //     73,728 B
  uint4*          OFS   = (uint4*)(ws + 8462848);             //  9,437,184 B

  prep_kernel<<<1537, 256, 0, stream>>>(x_main, x_extra, pre_offset, pre_sim,
                                        weight, w_om, b_om, xT, Wfrag, OFS);
  dcn_main<<<1024, 256, 0, stream>>>(xT, Wfrag, OFS, bias, out);
}